// Round 13
// baseline (77.426 us; speedup 1.0000x reference)
//
#include <hip/hip_runtime.h>
#include <hip/hip_bf16.h>

// GAT layer, N=4096, FIN=512, H=4 heads, F=64.
// R13: K01 occupancy fix. R12 analysis: pack waves drain in ~15us, leaving a
// gemm-only tail at 2 blocks/CU (8 waves) -> Occ 49%, VALU 24%. Change: gemm
// blocks go 256->512 threads (1x4 micro, same FMA order -> bitwise-same XW),
// pack gets 2 loads in flight (vmcnt(1) not vmcnt(0) before ballot).
// Grid 1024 x 512thr = 4 blocks/CU = 32 waves/CU nominal.
//   K01: blocks<512 = GEMM 32x64 (512thr, 1x4) + scores + V-transpose;
//        blocks>=512 = mask-pack x2-deep.
//   K3:  64 rows/block, 20 MFMA/cc, raw v_exp_f32, trunc-packed P,
//        no max-subtraction (scores bounded -> softmax exact). (R10)
//   K4:  float4 combine, normalize, ELU. (R8)
// ws: pacc njb*4MB | f1h | f2h | Vhi 2MB | plsum | Ab 2MB. njb: 8 else 4.

#define NN   4096
#define FIN  512
#define H    4
#define F    64
#define HF   256
#define LOG2E 1.44269504088896340736f

typedef __attribute__((ext_vector_type(4))) float f32x4;
typedef __attribute__((ext_vector_type(8))) short short8;

union U8 { short8 s; unsigned int w[4]; };

// ---------------- K01: fused (GEMM+scores+transpose) | mask-pack ----------
// grid 1024 x 512thr: blocks 0..511 = gemm (bi=b&127, h=b>>7), 512..1023 = pack.
__global__ __launch_bounds__(512) void gemm_scores_pack(
        const float* __restrict__ X, const float* __restrict__ W,
        const float* __restrict__ a_src, const float* __restrict__ a_dst,
        const int* __restrict__ A,
        float* __restrict__ f1h, float* __restrict__ f2h,
        unsigned short* __restrict__ Vhi,
        unsigned long long* __restrict__ Ab) {
    if (blockIdx.x >= 512) {
        // ---- mask pack: 2 chunk-loads in flight per iter ----
        const int pb   = blockIdx.x - 512;                    // 0..511
        const int gw   = (pb * 512 + threadIdx.x) >> 6;       // 0..4095
        const int lane = threadIdx.x & 63;
        const int nchunk = NN * NN / 64;                      // 262144
        for (int c = gw; c < nchunk; c += 8192) {             // 32 iters
            int a0 = A[(size_t)c * 64 + lane];
            int a1 = A[(size_t)(c + 4096) * 64 + lane];
            unsigned long long m0 = __ballot(a0 != 0);
            unsigned long long m1 = __ballot(a1 != 0);
            if (lane == 0) {
                Ab[c] = m0;
                Ab[c + 4096] = m1;
            }
        }
        return;
    }

    __shared__ float Ast[32][34];            // [k][m]
    __shared__ float Bs[32][64];             // [k][n]
    __shared__ unsigned short Vt[64][40];    // [f][n]

    const int bi = blockIdx.x & 127, h = blockIdx.x >> 7;
    const int t  = threadIdx.x;
    const int tx = t & 15, ty = t >> 4;      // col*4, row (0..31)

    float acc[4];
#pragma unroll
    for (int c = 0; c < 4; ++c) acc[c] = 0.f;

    const int xr = t >> 4, xk = (t & 15) * 2;    // X stage: row, 2 k's
    const int wk = t >> 4, wn = (t & 15) * 4;    // W stage: k, 4 n's

    const float* Xp = X + (size_t)(bi * 32 + xr) * FIN + xk;
    const float* Wp = W + (size_t)wk * HF + h * F + wn;

    for (int k0 = 0; k0 < FIN; k0 += 32) {
        float2 xv = *(const float2*)(Xp + k0);
        float4 wv = *(const float4*)(Wp + (size_t)k0 * HF);
        __syncthreads();
        Ast[xk + 0][xr] = xv.x;
        Ast[xk + 1][xr] = xv.y;
        *(float4*)&Bs[wk][wn] = wv;
        __syncthreads();
#pragma unroll
        for (int kk = 0; kk < 32; ++kk) {
            float a = Ast[kk][ty];               // broadcast (16 lanes share)
            float4 b4 = *(const float4*)&Bs[kk][tx * 4];
            acc[0] += a * b4.x; acc[1] += a * b4.y;
            acc[2] += a * b4.z; acc[3] += a * b4.w;
        }
    }

    // scores: this thread owns row ty, cols tx*4+{0..3}; reduce over 16 tx
    float4 as4 = *(const float4*)(a_src + h * F + tx * 4);
    float4 ad4 = *(const float4*)(a_dst + h * F + tx * 4);
    {
        float s1 = acc[0] * as4.x + acc[1] * as4.y
                 + acc[2] * as4.z + acc[3] * as4.w;
        float s2 = acc[0] * ad4.x + acc[1] * ad4.y
                 + acc[2] * ad4.z + acc[3] * ad4.w;
#pragma unroll
        for (int off = 1; off < 16; off <<= 1) {
            s1 += __shfl_xor(s1, off, 16);
            s2 += __shfl_xor(s2, off, 16);
        }
        if (tx == 0) {
            const int n = bi * 32 + ty;
            f1h[h * NN + n] = s1 * LOG2E;
            f2h[h * NN + n] = s2 * LOG2E;
        }
    }

    // transposed bf16 V via LDS bounce
    __syncthreads();
#pragma unroll
    for (int c = 0; c < 4; ++c) {
        __hip_bfloat16 b = __float2bfloat16(acc[c]);
        Vt[tx * 4 + c][ty] = __builtin_bit_cast(unsigned short, b);
    }
    __syncthreads();
    {
        const int f = t >> 3, ch = t & 7;    // 64 f-rows x 8 chunks of 4 bf16
        ushort1 dummy;  (void)dummy;
        const unsigned short* src = &Vt[f][ch * 4];
        unsigned long long v = *(const unsigned long long*)src;   // 8B aligned
        unsigned short* dst = Vhi + (size_t)(h * F + f) * NN + bi * 32 + ch * 4;
        *(unsigned long long*)dst = v;
    }
}

// ---------------- K3: MFMA fused attention (partials) ----------------
// grid (64, njb): ib = 64-row block (4 rowtiles), jb = JLEN strip. wave=head.
template <int JLEN>
__global__ __launch_bounds__(256) void gat_attn_mfma(
        const unsigned int* __restrict__ Ab32,
        const unsigned short* __restrict__ Vhi,
        const float* __restrict__ f1h, const float* __restrict__ f2h,
        float* __restrict__ pacc, float* __restrict__ plsum) {
    constexpr int NCC = JLEN / 32;
    const int ib = blockIdx.x, jb = blockIdx.y;
    const int h    = threadIdx.x >> 6;
    const int lane = threadIdx.x & 63;
    const int il = lane & 15;        // MFMA A row / B,C/D col
    const int kg = lane >> 4;        // k-group
    const int sh = kg * 8;
    const int ibase = ib * 64 + il;

    float c[4];
#pragma unroll
    for (int rt = 0; rt < 4; ++rt) c[rt] = f1h[h * NN + ibase + rt * 16];

    const unsigned int* abp[4];
#pragma unroll
    for (int rt = 0; rt < 4; ++rt)
        abp[rt] = Ab32 + (size_t)(ibase + rt * 16) * (NN / 32) + jb * (JLEN / 32);

    const float* f2b = f2h + (size_t)h * NN + jb * JLEN + sh;

    const unsigned short* vb[4];
#pragma unroll
    for (int ft = 0; ft < 4; ++ft)
        vb[ft] = Vhi + (size_t)(h * F + ft * 16 + il) * NN + jb * JLEN + sh;

    f32x4 acc[4][4], lac[4];
#pragma unroll
    for (int rt = 0; rt < 4; ++rt) {
        lac[rt] = (f32x4){0.f, 0.f, 0.f, 0.f};
#pragma unroll
        for (int ft = 0; ft < 4; ++ft) acc[rt][ft] = (f32x4){0.f, 0.f, 0.f, 0.f};
    }

    short8 ones;
#pragma unroll
    for (int e = 0; e < 8; ++e) ones[e] = (short)0x3F80;   // bf16 1.0

#pragma unroll 2
    for (int cc = 0; cc < NCC; ++cc) {
        unsigned int m[4];
#pragma unroll
        for (int rt = 0; rt < 4; ++rt) m[rt] = abp[rt][cc] >> sh;

        float4 ga = *(const float4*)(f2b + cc * 32);
        float4 gb = *(const float4*)(f2b + cc * 32 + 4);
        float gv[8] = {ga.x, ga.y, ga.z, ga.w, gb.x, gb.y, gb.z, gb.w};

        short8 bh[4];
#pragma unroll
        for (int ft = 0; ft < 4; ++ft)
            bh[ft] = *reinterpret_cast<const short8*>(vb[ft] + cc * 32);

#pragma unroll
        for (int rt = 0; rt < 4; ++rt) {
            float pf[8];
#pragma unroll
            for (int e = 0; e < 8; ++e) {
                float s = c[rt] + gv[e];
                s = fmaxf(s, 0.2f * s);                 // leaky relu
                float q = __builtin_amdgcn_exp2f(s);    // raw v_exp_f32
                pf[e] = ((m[rt] >> e) & 1u) ? q : 0.f;
            }
            U8 pa;
#pragma unroll
            for (int e = 0; e < 8; e += 2)
                pa.w[e >> 1] = __builtin_amdgcn_perm(__float_as_uint(pf[e + 1]),
                                                     __float_as_uint(pf[e]),
                                                     0x07060302u);
#pragma unroll
            for (int ft = 0; ft < 4; ++ft)
                acc[rt][ft] = __builtin_amdgcn_mfma_f32_16x16x32_bf16(
                    pa.s, bh[ft], acc[rt][ft], 0, 0, 0);
            lac[rt] = __builtin_amdgcn_mfma_f32_16x16x32_bf16(
                pa.s, ones, lac[rt], 0, 0, 0);
        }
    }

    // C/D layout: col = lane&15, row = (lane>>4)*4 + reg
    float* pb = pacc + (size_t)jb * NN * HF + (size_t)(ib * 64) * HF;
#pragma unroll
    for (int rt = 0; rt < 4; ++rt)
#pragma unroll
        for (int ft = 0; ft < 4; ++ft)
#pragma unroll
            for (int r = 0; r < 4; ++r)
                pb[(rt * 16 + kg * 4 + r) * HF + h * F + ft * 16 + il] = acc[rt][ft][r];

    if (il == 0) {   // ones-MFMA: every col holds the row sum; use col 0
#pragma unroll
        for (int rt = 0; rt < 4; ++rt)
#pragma unroll
            for (int r = 0; r < 4; ++r)
                plsum[(size_t)jb * NN * H
                      + (size_t)(ib * 64 + rt * 16 + kg * 4 + r) * H + h] = lac[rt][r];
    }
}

// ---------------- K4: combine partials, normalize, ELU (float4) ----------
__global__ __launch_bounds__(256) void finalize(
        const float* __restrict__ pacc, const float* __restrict__ plsum,
        const unsigned short* __restrict__ Vhi, float* __restrict__ out,
        int njb) {
    const int gid4 = blockIdx.x * 256 + threadIdx.x;   // 0 .. NN*HF/4-1
    const int i = gid4 >> 6, q = gid4 & 63;
    const int h = q >> 4;
    float4 a = make_float4(0.f, 0.f, 0.f, 0.f);
    float l = 0.f;
    for (int jb = 0; jb < njb; ++jb) {
        float4 p = *(const float4*)&pacc[(size_t)jb * NN * HF + (size_t)i * HF + q * 4];
        a.x += p.x; a.y += p.y; a.z += p.z; a.w += p.w;
        l += plsum[(size_t)jb * NN * H + (size_t)i * H + h];
    }
    float av[4] = {a.x, a.y, a.z, a.w};
    if (l == 0.f) {   // empty row: reference softmax degenerates to uniform
#pragma unroll
        for (int c = 0; c < 4; ++c) {
            const unsigned short* col = Vhi + (size_t)(q * 4 + c) * NN;
            float s = 0.f;
            for (int j = 0; j < NN; ++j)
                s += __uint_as_float(((unsigned int)col[j]) << 16);
            av[c] = s;
        }
        l = (float)NN;
    }
    const float rl = 1.0f / l;
    float4 o;
    float* op = &o.x;
#pragma unroll
    for (int c = 0; c < 4; ++c) {
        float v = av[c] * rl;
        op[c] = (v > 0.f) ? v : (__builtin_amdgcn_exp2f(v * LOG2E) - 1.f);
    }
    *(float4*)&out[(size_t)i * HF + q * 4] = o;
}

// ---------------- launch ----------------
extern "C" void kernel_launch(void* const* d_in, const int* in_sizes, int n_in,
                              void* d_out, int out_size, void* d_ws, size_t ws_size,
                              hipStream_t stream) {
    const float* X     = (const float*)d_in[0];
    const int*   A     = (const int*)d_in[1];
    const float* W     = (const float*)d_in[2];
    const float* a_src = (const float*)d_in[3];
    const float* a_dst = (const float*)d_in[4];
    float* out = (float*)d_out;

    const size_t fixed = (size_t)2 * NN * H * 4 + (size_t)HF * NN * 2
                       + (size_t)NN * NN / 8;
    auto need = [&](int njb) {
        return (size_t)njb * NN * HF * 4 + (size_t)njb * NN * H * 4 + fixed;
    };
    const int njb = (ws_size >= need(8)) ? 8 : 4;   // deterministic in ws_size

    float* pacc = (float*)d_ws;
    float* f1h  = pacc + (size_t)njb * NN * HF;
    float* f2h  = f1h + (size_t)NN * H;
    unsigned short* Vhi = (unsigned short*)(f2h + (size_t)NN * H);
    float* plsum = (float*)(Vhi + (size_t)HF * NN);
    unsigned long long* Ab = (unsigned long long*)(plsum + (size_t)njb * NN * H);

    gemm_scores_pack<<<1024, 512, 0, stream>>>(X, W, a_src, a_dst, A,
                                               f1h, f2h, Vhi, Ab);
    if (njb == 8)
        gat_attn_mfma<512><<<dim3(64, 8), 256, 0, stream>>>(
            (const unsigned int*)Ab, Vhi, f1h, f2h, pacc, plsum);
    else
        gat_attn_mfma<1024><<<dim3(64, 4), 256, 0, stream>>>(
            (const unsigned int*)Ab, Vhi, f1h, f2h, pacc, plsum);
    finalize<<<NN * HF / 4 / 256, 256, 0, stream>>>(pacc, plsum, Vhi, out, njb);
}